// Round 4
// baseline (1261.404 us; speedup 1.0000x reference)
//
#include <hip/hip_runtime.h>
#include <hip/hip_bf16.h>
#include <cfloat>
#include <math.h>

#define T_TOK 4096
#define H_DIM 2048
#define E_NUM 64
#define I_DIM 1024
#define TOPK  8
#define BM    256
#define BK    64
#define MAXT  192   // max Sum_e ceil(cnt_e/BM) = 32768/256 + 64

typedef __attribute__((ext_vector_type(4))) float f32x4;
typedef __attribute__((ext_vector_type(8))) short bf16x8;
typedef __attribute__((ext_vector_type(4))) int   i32x4;

__device__ __forceinline__ unsigned short f2bf(float f) {
    union { float f; unsigned int u; } v; v.f = f;
    unsigned int r = v.u + 0x7FFFu + ((v.u >> 16) & 1u);  // RNE
    return (unsigned short)(r >> 16);
}
__device__ __forceinline__ unsigned int pack2(float a, float b) {
    return (unsigned int)f2bf(a) | ((unsigned int)f2bf(b) << 16);
}
__device__ __forceinline__ float bf2f(unsigned short u) {
    union { unsigned int u; float f; } v; v.u = (unsigned int)u << 16; return v.f;
}
__device__ __forceinline__ int cvtpk(float lo, float hi) {
    int r; asm("v_cvt_pk_bf16_f32 %0, %1, %2" : "=v"(r) : "v"(lo), "v"(hi)); return r;
}
__device__ __forceinline__ void gload16(const void* g, void* l) {
    __builtin_amdgcn_global_load_lds((const __attribute__((address_space(1))) unsigned int*)g,
                                     (__attribute__((address_space(3))) unsigned int*)l, 16, 0, 0);
}

// ---------------------------------------------------------------- router
__global__ __launch_bounds__(256)
void router_kernel(const float* __restrict__ x, const float* __restrict__ gw,
                   const float* __restrict__ gb, unsigned short* __restrict__ xb,
                   int* __restrict__ topk_idx, float* __restrict__ topk_w,
                   int* __restrict__ counts)
{
    const int t = blockIdx.x;
    const int tid = threadIdx.x;
    __shared__ float xs[H_DIM];
    __shared__ float logits[E_NUM];
    const float* xrow = x + (size_t)t * H_DIM;

    #pragma unroll
    for (int i = 0; i < 2; ++i) {
        int c = i * 1024 + tid * 4;
        f32x4 v = *(const f32x4*)(xrow + c);
        *(f32x4*)(xs + c) = v;
        uint2 pk; pk.x = pack2(v.x, v.y); pk.y = pack2(v.z, v.w);
        *(uint2*)(xb + (size_t)t * H_DIM + c) = pk;
    }
    __syncthreads();

    const int wave = tid >> 6, lane = tid & 63;
    for (int ee = 0; ee < 16; ++ee) {
        const int e = wave * 16 + ee;
        const float* g = gw + (size_t)e * H_DIM;
        float p = 0.f;
        #pragma unroll
        for (int i = 0; i < 8; ++i) {
            int c = (i * 64 + lane) * 4;
            f32x4 gv = *(const f32x4*)(g + c);
            f32x4 xv = *(const f32x4*)(xs + c);
            p += gv.x * xv.x + gv.y * xv.y + gv.z * xv.z + gv.w * xv.w;
        }
        #pragma unroll
        for (int s = 32; s > 0; s >>= 1) p += __shfl_xor(p, s, 64);
        if (lane == 0) logits[e] = p + gb[e];
    }
    __syncthreads();

    if (tid < 64) {
        float cur = logits[tid];
        float wv[TOPK]; int wi[TOPK];
        #pragma unroll
        for (int k = 0; k < TOPK; ++k) {
            float bv = cur; int bi = tid;
            #pragma unroll
            for (int s = 32; s > 0; s >>= 1) {
                float ov = __shfl_xor(bv, s, 64);
                int   oi = __shfl_xor(bi, s, 64);
                if (ov > bv || (ov == bv && oi < bi)) { bv = ov; bi = oi; }
            }
            wv[k] = bv; wi[k] = bi;
            if (tid == bi) cur = -FLT_MAX;
        }
        if (tid == 0) {
            float mx = wv[0], sum = 0.f, ex[TOPK];
            #pragma unroll
            for (int k = 0; k < TOPK; ++k) { ex[k] = expf(wv[k] - mx); sum += ex[k]; }
            #pragma unroll
            for (int k = 0; k < TOPK; ++k) {
                topk_idx[t * TOPK + k] = wi[k];
                topk_w[t * TOPK + k]   = ex[k] / sum;
                atomicAdd(&counts[wi[k]], 1);
            }
        }
    }
}

// ---------------------------------------------------------------- scan + tile list
__global__ void scan_kernel(const int* __restrict__ counts, int* __restrict__ offsets,
                            int* __restrict__ cursors, int* __restrict__ tiles,
                            int* __restrict__ ntiles)
{
    if (threadIdx.x == 0) {
        int acc = 0, nt = 0;
        for (int e = 0; e < E_NUM; ++e) {
            offsets[e] = acc; cursors[e] = acc;
            int c = counts[e];
            for (int m = 0; m * BM < c; ++m) tiles[nt++] = (e << 16) | m;
            acc += c;
        }
        *ntiles = nt;
    }
}

// ---------------------------------------------------------------- scatter assignments
__global__ void assign_kernel(const int* __restrict__ topk_idx, const float* __restrict__ topk_w,
                              int* __restrict__ cursors, int* __restrict__ tok_of,
                              int* __restrict__ pos_of)
{
    int i = blockIdx.x * 256 + threadIdx.x;
    if (i >= T_TOK * TOPK) return;
    int e = topk_idx[i];
    int pos = atomicAdd(&cursors[e], 1);
    tok_of[pos] = i >> 3;
    pos_of[i]   = pos;
}

// ---------------------------------------------------------------- GEMM1: 256x(128h+128g), fused fp32->bf16
__global__ __launch_bounds__(512, 1)
void gemm1_kernel(const unsigned short* __restrict__ xb, const float* __restrict__ fc1,
                  const int* __restrict__ counts, const int* __restrict__ offsets,
                  const int* __restrict__ tok_of, const int* __restrict__ tiles,
                  const int* __restrict__ ntiles, unsigned short* __restrict__ a_all)
{
    const int ty = blockIdx.y;
    if (ty >= *ntiles) return;
    const int code = tiles[ty];
    const int e = code >> 16, m0 = (code & 0xffff) * BM;
    const int cnt = counts[e], off = offsets[e];
    const int n0 = blockIdx.x * 128;             // pair-col block
    const float* W = fc1 + (size_t)e * (size_t)(2 * I_DIM) * H_DIM;

    __shared__ unsigned short sA[2][BM * BK];    // 2 x 32 KB
    __shared__ unsigned short sB[2 * 128 * BK];  // 32 KB: h rows 0..127, g rows 128..255
    __shared__ int sTok[BM];

    const int tid = threadIdx.x;
    if (tid < BM) {
        int m = m0 + tid;
        sTok[tid] = tok_of[off + (m < cnt ? m : cnt - 1)];
    }
    __syncthreads();

    const int wid = tid >> 6, lane = tid & 63;
    const int srow = tid >> 3, sch = tid & 7;    // srow 0..63
    const int sslot = sch ^ (srow & 7);          // pre-swizzled source slot (rule #21)

    const unsigned short* aSrc[4];
    const float* bSrc[4];
    #pragma unroll
    for (int i = 0; i < 4; ++i) {
        int row = srow + 64 * i;                 // 0..255
        aSrc[i] = xb + (size_t)sTok[row] * H_DIM + sslot * 8;
        int wrow = (row < 128) ? (n0 + row) : (I_DIM + n0 + (row - 128));
        bSrc[i] = W + (size_t)wrow * H_DIM + sch * 8;
    }

    f32x4 accH[4][4], accG[4][4];
    #pragma unroll
    for (int m = 0; m < 4; ++m)
        #pragma unroll
        for (int n = 0; n < 4; ++n) {
            accH[m][n] = (f32x4){0.f, 0.f, 0.f, 0.f};
            accG[m][n] = (f32x4){0.f, 0.f, 0.f, 0.f};
        }

    const int wm = (wid >> 1) * 64;              // 4 M groups of 64
    const int wnp = (wid & 1) * 64;              // 2 pair-col groups of 64
    const int fr = lane & 15;
    const int kg = lane >> 4;

    f32x4 br[8];                                 // 32 VGPR in-flight B

    auto issueB = [&](int k0) {
        #pragma unroll
        for (int i = 0; i < 4; ++i) {
            br[2 * i]     = *(const f32x4*)(bSrc[i] + k0);
            br[2 * i + 1] = *(const f32x4*)(bSrc[i] + k0 + 4);
        }
    };
    auto issueA = [&](int k0, int buf) {
        #pragma unroll
        for (int i = 0; i < 4; ++i)
            gload16(aSrc[i] + k0, &sA[buf][(64 * i + 8 * wid) * BK]);
    };
    auto writeB = [&]() {
        #pragma unroll
        for (int i = 0; i < 4; ++i) {
            int row = srow + 64 * i;
            i32x4 pk = (i32x4){cvtpk(br[2*i].x,   br[2*i].y),
                               cvtpk(br[2*i].z,   br[2*i].w),
                               cvtpk(br[2*i+1].x, br[2*i+1].y),
                               cvtpk(br[2*i+1].z, br[2*i+1].w)};
            int byte = (row * 128 + sch * 16) ^ ((row & 7) << 4);
            *(i32x4*)((char*)sB + byte) = pk;
        }
    };
    auto compute = [&](int buf) {
        #pragma unroll
        for (int kk = 0; kk < 2; ++kk) {
            bf16x8 af[4], bh[4], bg[4];
            #pragma unroll
            for (int m = 0; m < 4; ++m) {
                int row = wm + m * 16 + fr;
                af[m] = *(const bf16x8*)((const char*)sA[buf] +
                        ((row * 128 + kk * 64 + kg * 16) ^ ((row & 7) << 4)));
            }
            #pragma unroll
            for (int n = 0; n < 4; ++n) {
                int rh = wnp + n * 16 + fr;
                bh[n] = *(const bf16x8*)((const char*)sB +
                        ((rh * 128 + kk * 64 + kg * 16) ^ ((rh & 7) << 4)));
                int rg = 128 + rh;
                bg[n] = *(const bf16x8*)((const char*)sB +
                        ((rg * 128 + kk * 64 + kg * 16) ^ ((rg & 7) << 4)));
            }
            #pragma unroll
            for (int m = 0; m < 4; ++m)
                #pragma unroll
                for (int n = 0; n < 4; ++n) {
                    accH[m][n] = __builtin_amdgcn_mfma_f32_16x16x32_bf16(af[m], bh[n], accH[m][n], 0, 0, 0);
                    accG[m][n] = __builtin_amdgcn_mfma_f32_16x16x32_bf16(af[m], bg[n], accG[m][n], 0, 0, 0);
                }
        }
    };

    const int NT = H_DIM / BK;                   // 32
    issueB(0);
    issueA(0, 0);
    __syncthreads();
    writeB();
    __syncthreads();
    int cur = 0;
    for (int t = 0; t < NT; ++t) {
        const bool more = (t + 1) < NT;
        if (more) { issueB((t + 1) * BK); issueA((t + 1) * BK, cur ^ 1); }
        compute(cur);
        __syncthreads();
        if (more) writeB();
        __syncthreads();
        cur ^= 1;
    }

    #pragma unroll
    for (int m = 0; m < 4; ++m) {
        int rbase = wm + m * 16 + kg * 4;
        #pragma unroll
        for (int r = 0; r < 4; ++r) {
            int gm = m0 + rbase + r;
            if (gm < cnt) {
                size_t rowoff = (size_t)(off + gm) * I_DIM + n0 + wnp;
                #pragma unroll
                for (int n = 0; n < 4; ++n) {
                    float h = accH[m][n][r];
                    float g = accG[m][n][r];
                    float a = 0.5f * h * (1.f + erff(h * 0.70710678118f)) * (g + 1.f);
                    a_all[rowoff + n * 16 + fr] = f2bf(a);
                }
            }
        }
    }
}

// ---------------------------------------------------------------- GEMM2: 256x128, fused fp32->bf16, bf16 y out
__global__ __launch_bounds__(512, 1)
void gemm2_kernel(const unsigned short* __restrict__ a_all, const float* __restrict__ fc2,
                  const int* __restrict__ counts, const int* __restrict__ offsets,
                  const int* __restrict__ tiles, const int* __restrict__ ntiles,
                  unsigned short* __restrict__ y)
{
    const int ty = blockIdx.y;
    if (ty >= *ntiles) return;
    const int code = tiles[ty];
    const int e = code >> 16, m0 = (code & 0xffff) * BM;
    const int cnt = counts[e], off = offsets[e];
    const int n0 = blockIdx.x * 128;
    const float* W = fc2 + (size_t)e * (size_t)H_DIM * I_DIM;

    __shared__ unsigned short sA[2][BM * BK];    // 2 x 32 KB
    __shared__ unsigned short sB[128 * BK];      // 16 KB

    const int tid = threadIdx.x;
    const int wid = tid >> 6, lane = tid & 63;
    const int srow = tid >> 3, sch = tid & 7;
    const int sslot = sch ^ (srow & 7);

    const unsigned short* aSrc[4];
    const float* bSrc[2];
    #pragma unroll
    for (int i = 0; i < 4; ++i) {
        int row = srow + 64 * i;
        aSrc[i] = a_all + (size_t)(off + m0 + row) * I_DIM + sslot * 8;
    }
    #pragma unroll
    for (int i = 0; i < 2; ++i) {
        int row = srow + 64 * i;                 // 0..127
        bSrc[i] = W + (size_t)(n0 + row) * I_DIM + sch * 8;
    }

    f32x4 acc[4][4];
    #pragma unroll
    for (int m = 0; m < 4; ++m)
        #pragma unroll
        for (int n = 0; n < 4; ++n) acc[m][n] = (f32x4){0.f, 0.f, 0.f, 0.f};

    const int wm = (wid >> 1) * 64;
    const int wn = (wid & 1) * 64;
    const int fr = lane & 15;
    const int kg = lane >> 4;

    f32x4 br[4];

    auto issueB = [&](int k0) {
        #pragma unroll
        for (int i = 0; i < 2; ++i) {
            br[2 * i]     = *(const f32x4*)(bSrc[i] + k0);
            br[2 * i + 1] = *(const f32x4*)(bSrc[i] + k0 + 4);
        }
    };
    auto issueA = [&](int k0, int buf) {
        #pragma unroll
        for (int i = 0; i < 4; ++i)
            gload16(aSrc[i] + k0, &sA[buf][(64 * i + 8 * wid) * BK]);
    };
    auto writeB = [&]() {
        #pragma unroll
        for (int i = 0; i < 2; ++i) {
            int row = srow + 64 * i;
            i32x4 pk = (i32x4){cvtpk(br[2*i].x,   br[2*i].y),
                               cvtpk(br[2*i].z,   br[2*i].w),
                               cvtpk(br[2*i+1].x, br[2*i+1].y),
                               cvtpk(br[2*i+1].z, br[2*i+1].w)};
            int byte = (row * 128 + sch * 16) ^ ((row & 7) << 4);
            *(i32x4*)((char*)sB + byte) = pk;
        }
    };
    auto compute = [&](int buf) {
        #pragma unroll
        for (int kk = 0; kk < 2; ++kk) {
            bf16x8 af[4], bfr[4];
            #pragma unroll
            for (int m = 0; m < 4; ++m) {
                int row = wm + m * 16 + fr;
                af[m] = *(const bf16x8*)((const char*)sA[buf] +
                        ((row * 128 + kk * 64 + kg * 16) ^ ((row & 7) << 4)));
            }
            #pragma unroll
            for (int n = 0; n < 4; ++n) {
                int row = wn + n * 16 + fr;
                bfr[n] = *(const bf16x8*)((const char*)sB +
                        ((row * 128 + kk * 64 + kg * 16) ^ ((row & 7) << 4)));
            }
            #pragma unroll
            for (int m = 0; m < 4; ++m)
                #pragma unroll
                for (int n = 0; n < 4; ++n)
                    acc[m][n] = __builtin_amdgcn_mfma_f32_16x16x32_bf16(af[m], bfr[n], acc[m][n], 0, 0, 0);
        }
    };

    const int NT = I_DIM / BK;                   // 16
    issueB(0);
    issueA(0, 0);
    __syncthreads();
    writeB();
    __syncthreads();
    int cur = 0;
    for (int t = 0; t < NT; ++t) {
        const bool more = (t + 1) < NT;
        if (more) { issueB((t + 1) * BK); issueA((t + 1) * BK, cur ^ 1); }
        compute(cur);
        __syncthreads();
        if (more) writeB();
        __syncthreads();
        cur ^= 1;
    }

    #pragma unroll
    for (int m = 0; m < 4; ++m) {
        int rbase = wm + m * 16 + kg * 4;
        #pragma unroll
        for (int r = 0; r < 4; ++r) {
            int gm = m0 + rbase + r;
            if (gm < cnt) {
                size_t rowoff = (size_t)(off + gm) * H_DIM + n0 + wn;
                #pragma unroll
                for (int n = 0; n < 4; ++n)
                    y[rowoff + n * 16 + fr] = f2bf(acc[m][n][r]);
            }
        }
    }
}

// ---------------------------------------------------------------- combine: out[t] = sum_k w_k * y[pos_k]
__global__ __launch_bounds__(256)
void combine_kernel(const unsigned short* __restrict__ y, const int* __restrict__ pos_of,
                    const float* __restrict__ topk_w, float* __restrict__ out)
{
    const int t = blockIdx.x;
    const int tid = threadIdx.x;
    __shared__ int   sp[TOPK];
    __shared__ float sw[TOPK];
    if (tid < TOPK) {
        sp[tid] = pos_of[t * TOPK + tid];
        sw[tid] = topk_w[t * TOPK + tid];
    }
    __syncthreads();

    const int c0 = tid * 8;
    float acc[8];
    #pragma unroll
    for (int j = 0; j < 8; ++j) acc[j] = 0.f;
    #pragma unroll
    for (int k = 0; k < TOPK; ++k) {
        const float w = sw[k];
        i32x4 v = *(const i32x4*)(y + (size_t)sp[k] * H_DIM + c0);
        const unsigned short* u = (const unsigned short*)&v;
        #pragma unroll
        for (int j = 0; j < 8; ++j) acc[j] += w * bf2f(u[j]);
    }
    float* orow = out + (size_t)t * H_DIM + c0;
    *(f32x4*)orow       = (f32x4){acc[0], acc[1], acc[2], acc[3]};
    *(f32x4*)(orow + 4) = (f32x4){acc[4], acc[5], acc[6], acc[7]};
}

// ---------------------------------------------------------------- launch
extern "C" void kernel_launch(void* const* d_in, const int* in_sizes, int n_in,
                              void* d_out, int out_size, void* d_ws, size_t ws_size,
                              hipStream_t stream)
{
    const float* x   = (const float*)d_in[0];
    const float* gw  = (const float*)d_in[1];
    const float* gb  = (const float*)d_in[2];
    const float* fc1 = (const float*)d_in[3];
    const float* fc2 = (const float*)d_in[4];
    float* out = (float*)d_out;

    char* ws = (char*)d_ws;
    size_t o = 0;
    auto alloc = [&](size_t b) { void* p = ws + o; o = (o + b + 255) & ~(size_t)255; return p; };
    unsigned short* xb     = (unsigned short*)alloc((size_t)T_TOK * H_DIM * 2);
    int*            tk_idx = (int*)  alloc((size_t)T_TOK * TOPK * 4);
    float*          tk_w   = (float*)alloc((size_t)T_TOK * TOPK * 4);
    int*            counts = (int*)  alloc(E_NUM * 4);
    int*            offs   = (int*)  alloc(E_NUM * 4);
    int*            curs   = (int*)  alloc(E_NUM * 4);
    int*            tiles  = (int*)  alloc(MAXT * 4);
    int*            ntiles = (int*)  alloc(4);
    int*            tok_of = (int*)  alloc((size_t)T_TOK * TOPK * 4);
    int*            pos_of = (int*)  alloc((size_t)T_TOK * TOPK * 4);
    unsigned short* a_all  = (unsigned short*)alloc((size_t)(T_TOK * TOPK + BM) * I_DIM * 2);
    unsigned short* yb     = (unsigned short*)alloc((size_t)T_TOK * TOPK * H_DIM * 2);
    (void)ws_size;

    hipMemsetAsync(counts, 0, E_NUM * 4, stream);

    router_kernel<<<T_TOK, 256, 0, stream>>>(x, gw, gb, xb, tk_idx, tk_w, counts);
    scan_kernel<<<1, 64, 0, stream>>>(counts, offs, curs, tiles, ntiles);
    assign_kernel<<<(T_TOK * TOPK + 255) / 256, 256, 0, stream>>>(tk_idx, tk_w, curs, tok_of, pos_of);
    gemm1_kernel<<<dim3(I_DIM / 128, MAXT), 512, 0, stream>>>(xb, fc1, counts, offs, tok_of,
                                                              tiles, ntiles, a_all);
    gemm2_kernel<<<dim3(H_DIM / 128, MAXT), 512, 0, stream>>>(a_all, fc2, counts, offs,
                                                              tiles, ntiles, yb);
    combine_kernel<<<T_TOK, 256, 0, stream>>>(yb, pos_of, tk_w, out);
}

// Round 5
// 1144.563 us; speedup vs baseline: 1.1021x; 1.1021x over previous
//
#include <hip/hip_runtime.h>
#include <hip/hip_bf16.h>
#include <cfloat>
#include <math.h>

#define T_TOK 4096
#define H_DIM 2048
#define E_NUM 64
#define I_DIM 1024
#define TOPK  8
#define BM    640   // covers cnt ~ N(512,21) in one tile (>6 sigma); multi-tile fallback kept
#define BK    64
#define MAXT  128   // worst case: 32768/640 + 63 = 115

typedef __attribute__((ext_vector_type(4))) float f32x4;
typedef __attribute__((ext_vector_type(8))) short bf16x8;
typedef __attribute__((ext_vector_type(4))) int   i32x4;

__device__ __forceinline__ unsigned short f2bf(float f) {
    union { float f; unsigned int u; } v; v.f = f;
    unsigned int r = v.u + 0x7FFFu + ((v.u >> 16) & 1u);  // RNE
    return (unsigned short)(r >> 16);
}
__device__ __forceinline__ unsigned int pack2(float a, float b) {
    return (unsigned int)f2bf(a) | ((unsigned int)f2bf(b) << 16);
}
__device__ __forceinline__ float bf2f(unsigned short u) {
    union { unsigned int u; float f; } v; v.u = (unsigned int)u << 16; return v.f;
}
__device__ __forceinline__ int cvtpk(float lo, float hi) {
    int r; asm("v_cvt_pk_bf16_f32 %0, %1, %2" : "=v"(r) : "v"(lo), "v"(hi)); return r;
}
__device__ __forceinline__ void gload16(const void* g, void* l) {
    __builtin_amdgcn_global_load_lds((const __attribute__((address_space(1))) unsigned int*)g,
                                     (__attribute__((address_space(3))) unsigned int*)l, 16, 0, 0);
}

// ---------------------------------------------------------------- router
__global__ __launch_bounds__(256)
void router_kernel(const float* __restrict__ x, const float* __restrict__ gw,
                   const float* __restrict__ gb, unsigned short* __restrict__ xb,
                   int* __restrict__ topk_idx, float* __restrict__ topk_w,
                   int* __restrict__ counts)
{
    const int t = blockIdx.x;
    const int tid = threadIdx.x;
    __shared__ float xs[H_DIM];
    __shared__ float logits[E_NUM];
    const float* xrow = x + (size_t)t * H_DIM;

    #pragma unroll
    for (int i = 0; i < 2; ++i) {
        int c = i * 1024 + tid * 4;
        f32x4 v = *(const f32x4*)(xrow + c);
        *(f32x4*)(xs + c) = v;
        uint2 pk; pk.x = pack2(v.x, v.y); pk.y = pack2(v.z, v.w);
        *(uint2*)(xb + (size_t)t * H_DIM + c) = pk;
    }
    __syncthreads();

    const int wave = tid >> 6, lane = tid & 63;
    for (int ee = 0; ee < 16; ++ee) {
        const int e = wave * 16 + ee;
        const float* g = gw + (size_t)e * H_DIM;
        float p = 0.f;
        #pragma unroll
        for (int i = 0; i < 8; ++i) {
            int c = (i * 64 + lane) * 4;
            f32x4 gv = *(const f32x4*)(g + c);
            f32x4 xv = *(const f32x4*)(xs + c);
            p += gv.x * xv.x + gv.y * xv.y + gv.z * xv.z + gv.w * xv.w;
        }
        #pragma unroll
        for (int s = 32; s > 0; s >>= 1) p += __shfl_xor(p, s, 64);
        if (lane == 0) logits[e] = p + gb[e];
    }
    __syncthreads();

    if (tid < 64) {
        float cur = logits[tid];
        float wv[TOPK]; int wi[TOPK];
        #pragma unroll
        for (int k = 0; k < TOPK; ++k) {
            float bv = cur; int bi = tid;
            #pragma unroll
            for (int s = 32; s > 0; s >>= 1) {
                float ov = __shfl_xor(bv, s, 64);
                int   oi = __shfl_xor(bi, s, 64);
                if (ov > bv || (ov == bv && oi < bi)) { bv = ov; bi = oi; }
            }
            wv[k] = bv; wi[k] = bi;
            if (tid == bi) cur = -FLT_MAX;
        }
        if (tid == 0) {
            float mx = wv[0], sum = 0.f, ex[TOPK];
            #pragma unroll
            for (int k = 0; k < TOPK; ++k) { ex[k] = expf(wv[k] - mx); sum += ex[k]; }
            #pragma unroll
            for (int k = 0; k < TOPK; ++k) {
                topk_idx[t * TOPK + k] = wi[k];
                topk_w[t * TOPK + k]   = ex[k] / sum;
                atomicAdd(&counts[wi[k]], 1);
            }
        }
    }
}

// ---------------------------------------------------------------- scan + tile list
__global__ void scan_kernel(const int* __restrict__ counts, int* __restrict__ offsets,
                            int* __restrict__ cursors, int* __restrict__ tiles,
                            int* __restrict__ ntiles)
{
    if (threadIdx.x == 0) {
        int acc = 0, nt = 0;
        for (int e = 0; e < E_NUM; ++e) {
            offsets[e] = acc; cursors[e] = acc;
            int c = counts[e];
            for (int m = 0; m * BM < c; ++m) tiles[nt++] = (e << 16) | m;
            acc += c;
        }
        *ntiles = nt;
    }
}

// ---------------------------------------------------------------- scatter assignments
__global__ void assign_kernel(const int* __restrict__ topk_idx, const float* __restrict__ topk_w,
                              int* __restrict__ cursors, int* __restrict__ tok_of,
                              int* __restrict__ pos_of)
{
    int i = blockIdx.x * 256 + threadIdx.x;
    if (i >= T_TOK * TOPK) return;
    int e = topk_idx[i];
    int pos = atomicAdd(&cursors[e], 1);
    tok_of[pos] = i >> 3;
    pos_of[i]   = pos;
}

// ---------------------------------------------------------------- GEMM1: 640 x (64h+64g), weights read ONCE
__global__ __launch_bounds__(512, 1)
void gemm1_kernel(const unsigned short* __restrict__ xb, const float* __restrict__ fc1,
                  const int* __restrict__ counts, const int* __restrict__ offsets,
                  const int* __restrict__ tok_of, const int* __restrict__ tiles,
                  const int* __restrict__ ntiles, unsigned short* __restrict__ a_all)
{
    const int ty = blockIdx.y;
    if (ty >= *ntiles) return;
    const int code = tiles[ty];
    const int e = code >> 16, m0 = (code & 0xffff) * BM;
    const int cnt = counts[e], off = offsets[e];
    const int n0 = blockIdx.x * 64;              // pair-col strip of 64
    const float* W = fc1 + (size_t)e * (size_t)(2 * I_DIM) * H_DIM;

    __shared__ unsigned short sA[BM * BK];       // 80 KB, single buffer
    __shared__ unsigned short sB[128 * BK];      // 16 KB (64 h rows + 64 g rows)
    __shared__ int sTok[BM];

    const int tid = threadIdx.x;
    {
        int r0 = m0 + tid;
        sTok[tid] = tok_of[off + (r0 < cnt ? r0 : cnt - 1)];
        if (tid < BM - 512) {
            int r1 = m0 + 512 + tid;
            sTok[512 + tid] = tok_of[off + (r1 < cnt ? r1 : cnt - 1)];
        }
    }
    __syncthreads();

    const int wid = tid >> 6, lane = tid & 63;
    const int srow = tid >> 3, sch = tid & 7;    // srow 0..63
    const int sslot = sch ^ (srow & 7);          // pre-swizzled A source slot (rule #21)

    const unsigned short* aSrc[10];
    #pragma unroll
    for (int i = 0; i < 10; ++i) {
        int row = srow + 64 * i;                 // 0..639
        aSrc[i] = xb + (size_t)sTok[row] * H_DIM + sslot * 8;
    }
    const float* bSrc[2];
    #pragma unroll
    for (int i = 0; i < 2; ++i) {
        int row = srow + 64 * i;                 // 0..127: 0..63 = h, 64..127 = g
        int wrow = (row < 64) ? (n0 + row) : (I_DIM + n0 + (row - 64));
        bSrc[i] = W + (size_t)wrow * H_DIM + sch * 8;
    }

    f32x4 accH[5][4], accG[5][4];
    #pragma unroll
    for (int m = 0; m < 5; ++m)
        #pragma unroll
        for (int n = 0; n < 4; ++n) {
            accH[m][n] = (f32x4){0.f, 0.f, 0.f, 0.f};
            accG[m][n] = (f32x4){0.f, 0.f, 0.f, 0.f};
        }

    const int wm = wid * 80;                     // 8 waves x 80 rows
    const int fr = lane & 15;
    const int kg = lane >> 4;

    f32x4 br[4];                                 // in-flight B (16 VGPR)

    auto issueB = [&](int k0) {
        #pragma unroll
        for (int i = 0; i < 2; ++i) {
            br[2 * i]     = *(const f32x4*)(bSrc[i] + k0);
            br[2 * i + 1] = *(const f32x4*)(bSrc[i] + k0 + 4);
        }
    };
    auto issueA = [&](int k0) {
        #pragma unroll
        for (int i = 0; i < 10; ++i)
            gload16(aSrc[i] + k0, &sA[(64 * i + 8 * wid) * BK]);
    };
    auto writeB = [&]() {
        #pragma unroll
        for (int i = 0; i < 2; ++i) {
            int row = srow + 64 * i;
            i32x4 pk = (i32x4){cvtpk(br[2*i].x,   br[2*i].y),
                               cvtpk(br[2*i].z,   br[2*i].w),
                               cvtpk(br[2*i+1].x, br[2*i+1].y),
                               cvtpk(br[2*i+1].z, br[2*i+1].w)};
            int byte = (row * 128 + sch * 16) ^ ((row & 7) << 4);
            *(i32x4*)((char*)sB + byte) = pk;
        }
    };
    auto compute = [&]() {
        #pragma unroll
        for (int kk = 0; kk < 2; ++kk) {
            bf16x8 af[5], bh[4], bg[4];
            #pragma unroll
            for (int m = 0; m < 5; ++m) {
                int row = wm + m * 16 + fr;
                af[m] = *(const bf16x8*)((const char*)sA +
                        ((row * 128 + kk * 64 + kg * 16) ^ ((row & 7) << 4)));
            }
            #pragma unroll
            for (int n = 0; n < 4; ++n) {
                int rh = n * 16 + fr;
                bh[n] = *(const bf16x8*)((const char*)sB +
                        ((rh * 128 + kk * 64 + kg * 16) ^ ((rh & 7) << 4)));
                int rg = 64 + rh;
                bg[n] = *(const bf16x8*)((const char*)sB +
                        ((rg * 128 + kk * 64 + kg * 16) ^ ((rg & 7) << 4)));
            }
            #pragma unroll
            for (int m = 0; m < 5; ++m)
                #pragma unroll
                for (int n = 0; n < 4; ++n) {
                    accH[m][n] = __builtin_amdgcn_mfma_f32_16x16x32_bf16(af[m], bh[n], accH[m][n], 0, 0, 0);
                    accG[m][n] = __builtin_amdgcn_mfma_f32_16x16x32_bf16(af[m], bg[n], accG[m][n], 0, 0, 0);
                }
        }
    };

    const int NT = H_DIM / BK;                   // 32
    issueB(0);
    issueA(0);
    __syncthreads();                             // drain: br0 + sA(0) landed
    writeB();
    __syncthreads();                             // sB(0) visible
    for (int t = 0; t < NT; ++t) {
        if (t + 1 < NT) issueB((t + 1) * BK);    // B loads fly under MFMA
        compute();
        __syncthreads();                         // reads done; br(t+1) landed (free drain)
        if (t + 1 < NT) { issueA((t + 1) * BK); writeB(); }
        __syncthreads();                         // sA(t+1) landed, sB(t+1) visible
    }

    #pragma unroll
    for (int m = 0; m < 5; ++m) {
        int rbase = wm + m * 16 + kg * 4;
        #pragma unroll
        for (int r = 0; r < 4; ++r) {
            int gm = m0 + rbase + r;
            if (gm < cnt) {
                size_t rowoff = (size_t)(off + gm) * I_DIM + n0;
                #pragma unroll
                for (int n = 0; n < 4; ++n) {
                    float h = accH[m][n][r];
                    float g = accG[m][n][r];
                    float a = 0.5f * h * (1.f + erff(h * 0.70710678118f)) * (g + 1.f);
                    a_all[rowoff + n * 16 + fr] = f2bf(a);
                }
            }
        }
    }
}

// ---------------------------------------------------------------- GEMM2: 640 x 128, weights read ONCE
__global__ __launch_bounds__(512, 1)
void gemm2_kernel(const unsigned short* __restrict__ a_all, const float* __restrict__ fc2,
                  const int* __restrict__ counts, const int* __restrict__ offsets,
                  const int* __restrict__ tiles, const int* __restrict__ ntiles,
                  unsigned short* __restrict__ y)
{
    const int ty = blockIdx.y;
    if (ty >= *ntiles) return;
    const int code = tiles[ty];
    const int e = code >> 16, m0 = (code & 0xffff) * BM;
    const int cnt = counts[e], off = offsets[e];
    const int n0 = blockIdx.x * 128;
    const float* W = fc2 + (size_t)e * (size_t)H_DIM * I_DIM;

    __shared__ unsigned short sA[BM * BK];       // 80 KB
    __shared__ unsigned short sB[128 * BK];      // 16 KB

    const int tid = threadIdx.x;
    const int wid = tid >> 6, lane = tid & 63;
    const int srow = tid >> 3, sch = tid & 7;
    const int sslot = sch ^ (srow & 7);

    const unsigned short* aSrc[10];
    #pragma unroll
    for (int i = 0; i < 10; ++i) {
        int row = srow + 64 * i;
        aSrc[i] = a_all + (size_t)(off + m0 + row) * I_DIM + sslot * 8;
    }
    const float* bSrc[2];
    #pragma unroll
    for (int i = 0; i < 2; ++i) {
        int row = srow + 64 * i;                 // 0..127
        bSrc[i] = W + (size_t)(n0 + row) * I_DIM + sch * 8;
    }

    f32x4 acc[5][8];
    #pragma unroll
    for (int m = 0; m < 5; ++m)
        #pragma unroll
        for (int n = 0; n < 8; ++n) acc[m][n] = (f32x4){0.f, 0.f, 0.f, 0.f};

    const int wm = wid * 80;
    const int fr = lane & 15;
    const int kg = lane >> 4;

    f32x4 br[4];

    auto issueB = [&](int k0) {
        #pragma unroll
        for (int i = 0; i < 2; ++i) {
            br[2 * i]     = *(const f32x4*)(bSrc[i] + k0);
            br[2 * i + 1] = *(const f32x4*)(bSrc[i] + k0 + 4);
        }
    };
    auto issueA = [&](int k0) {
        #pragma unroll
        for (int i = 0; i < 10; ++i)
            gload16(aSrc[i] + k0, &sA[(64 * i + 8 * wid) * BK]);
    };
    auto writeB = [&]() {
        #pragma unroll
        for (int i = 0; i < 2; ++i) {
            int row = srow + 64 * i;
            i32x4 pk = (i32x4){cvtpk(br[2*i].x,   br[2*i].y),
                               cvtpk(br[2*i].z,   br[2*i].w),
                               cvtpk(br[2*i+1].x, br[2*i+1].y),
                               cvtpk(br[2*i+1].z, br[2*i+1].w)};
            int byte = (row * 128 + sch * 16) ^ ((row & 7) << 4);
            *(i32x4*)((char*)sB + byte) = pk;
        }
    };
    auto compute = [&]() {
        #pragma unroll
        for (int kk = 0; kk < 2; ++kk) {
            bf16x8 af[5], bfr[8];
            #pragma unroll
            for (int m = 0; m < 5; ++m) {
                int row = wm + m * 16 + fr;
                af[m] = *(const bf16x8*)((const char*)sA +
                        ((row * 128 + kk * 64 + kg * 16) ^ ((row & 7) << 4)));
            }
            #pragma unroll
            for (int n = 0; n < 8; ++n) {
                int row = n * 16 + fr;
                bfr[n] = *(const bf16x8*)((const char*)sB +
                        ((row * 128 + kk * 64 + kg * 16) ^ ((row & 7) << 4)));
            }
            #pragma unroll
            for (int m = 0; m < 5; ++m)
                #pragma unroll
                for (int n = 0; n < 8; ++n)
                    acc[m][n] = __builtin_amdgcn_mfma_f32_16x16x32_bf16(af[m], bfr[n], acc[m][n], 0, 0, 0);
        }
    };

    const int NT = I_DIM / BK;                   // 16
    issueB(0);
    issueA(0);
    __syncthreads();
    writeB();
    __syncthreads();
    for (int t = 0; t < NT; ++t) {
        if (t + 1 < NT) issueB((t + 1) * BK);
        compute();
        __syncthreads();
        if (t + 1 < NT) { issueA((t + 1) * BK); writeB(); }
        __syncthreads();
    }

    #pragma unroll
    for (int m = 0; m < 5; ++m) {
        int rbase = wm + m * 16 + kg * 4;
        #pragma unroll
        for (int r = 0; r < 4; ++r) {
            int gm = m0 + rbase + r;
            if (gm < cnt) {
                size_t rowoff = (size_t)(off + gm) * H_DIM + n0;
                #pragma unroll
                for (int n = 0; n < 8; ++n)
                    y[rowoff + n * 16 + fr] = f2bf(acc[m][n][r]);
            }
        }
    }
}

// ---------------------------------------------------------------- combine: out[t] = sum_k w_k * y[pos_k]
__global__ __launch_bounds__(256)
void combine_kernel(const unsigned short* __restrict__ y, const int* __restrict__ pos_of,
                    const float* __restrict__ topk_w, float* __restrict__ out)
{
    const int t = blockIdx.x;
    const int tid = threadIdx.x;
    __shared__ int   sp[TOPK];
    __shared__ float sw[TOPK];
    if (tid < TOPK) {
        sp[tid] = pos_of[t * TOPK + tid];
        sw[tid] = topk_w[t * TOPK + tid];
    }
    __syncthreads();

    const int c0 = tid * 8;
    float acc[8];
    #pragma unroll
    for (int j = 0; j < 8; ++j) acc[j] = 0.f;
    #pragma unroll
    for (int k = 0; k < TOPK; ++k) {
        const float w = sw[k];
        i32x4 v = *(const i32x4*)(y + (size_t)sp[k] * H_DIM + c0);
        const unsigned short* u = (const unsigned short*)&v;
        #pragma unroll
        for (int j = 0; j < 8; ++j) acc[j] += w * bf2f(u[j]);
    }
    float* orow = out + (size_t)t * H_DIM + c0;
    *(f32x4*)orow       = (f32x4){acc[0], acc[1], acc[2], acc[3]};
    *(f32x4*)(orow + 4) = (f32x4){acc[4], acc[5], acc[6], acc[7]};
}

// ---------------------------------------------------------------- launch
extern "C" void kernel_launch(void* const* d_in, const int* in_sizes, int n_in,
                              void* d_out, int out_size, void* d_ws, size_t ws_size,
                              hipStream_t stream)
{
    const float* x   = (const float*)d_in[0];
    const float* gw  = (const float*)d_in[1];
    const float* gb  = (const float*)d_in[2];
    const float* fc1 = (const float*)d_in[3];
    const float* fc2 = (const float*)d_in[4];
    float* out = (float*)d_out;

    char* ws = (char*)d_ws;
    size_t o = 0;
    auto alloc = [&](size_t b) { void* p = ws + o; o = (o + b + 255) & ~(size_t)255; return p; };
    unsigned short* xb     = (unsigned short*)alloc((size_t)T_TOK * H_DIM * 2);
    int*            tk_idx = (int*)  alloc((size_t)T_TOK * TOPK * 4);
    float*          tk_w   = (float*)alloc((size_t)T_TOK * TOPK * 4);
    int*            counts = (int*)  alloc(E_NUM * 4);
    int*            offs   = (int*)  alloc(E_NUM * 4);
    int*            curs   = (int*)  alloc(E_NUM * 4);
    int*            tiles  = (int*)  alloc(MAXT * 4);
    int*            ntiles = (int*)  alloc(4);
    int*            tok_of = (int*)  alloc((size_t)T_TOK * TOPK * 4);
    int*            pos_of = (int*)  alloc((size_t)T_TOK * TOPK * 4);
    unsigned short* a_all  = (unsigned short*)alloc((size_t)(T_TOK * TOPK + BM) * I_DIM * 2);
    unsigned short* yb     = (unsigned short*)alloc((size_t)(T_TOK * TOPK + BM) * H_DIM * 2);
    (void)ws_size;

    hipMemsetAsync(counts, 0, E_NUM * 4, stream);

    router_kernel<<<T_TOK, 256, 0, stream>>>(x, gw, gb, xb, tk_idx, tk_w, counts);
    scan_kernel<<<1, 64, 0, stream>>>(counts, offs, curs, tiles, ntiles);
    assign_kernel<<<(T_TOK * TOPK + 255) / 256, 256, 0, stream>>>(tk_idx, tk_w, curs, tok_of, pos_of);
    gemm1_kernel<<<dim3(I_DIM / 64, MAXT), 512, 0, stream>>>(xb, fc1, counts, offs, tok_of,
                                                             tiles, ntiles, a_all);
    gemm2_kernel<<<dim3(H_DIM / 128, MAXT), 512, 0, stream>>>(a_all, fc2, counts, offs,
                                                              tiles, ntiles, yb);
    combine_kernel<<<T_TOK, 256, 0, stream>>>(yb, pos_of, tk_w, out);
}